// Round 7
// baseline (146.119 us; speedup 1.0000x reference)
//
#include <hip/hip_runtime.h>

#define Hd 128
#define Wd 128
#define Cd 64
#define COd 64
#define Bd 4
#define HWd (Hd*Wd)

typedef __attribute__((ext_vector_type(8))) short  short8;
typedef __attribute__((ext_vector_type(4))) float  f32x4;
typedef __attribute__((ext_vector_type(2))) float  f32x2;

// Static device scratch.
__device__ __align__(16) short g_wbf[COd*576];                   // bf16 W[co][k], k=t*64+c
__device__ __align__(16) float g_wtoff[9*Cd*4];                  // w_off^T [t][c][o]
__device__ float4 g_offs[Bd*HWd];                                // (off0, off1, s1, s2)
__device__ __align__(16) unsigned short g_xt[(size_t)Bd*HWd*Cd]; // bf16 NHWC x

static __device__ __forceinline__ unsigned short f2bf(float v) {
    unsigned u = __float_as_uint(v);
    u += 0x7FFFu + ((u >> 16) & 1u);   // RNE
    return (unsigned short)(u >> 16);
}
static __device__ __forceinline__ float bflo(unsigned u) { return __uint_as_float(u << 16); }
static __device__ __forceinline__ float bfhi(unsigned u) { return __uint_as_float(u & 0xFFFF0000u); }
static __device__ __forceinline__ f32x2 bf2(unsigned u) {
    return (f32x2){__uint_as_float(u << 16), __uint_as_float(u & 0xFFFF0000u)};
}
static __device__ __forceinline__ unsigned cvtpk(float lo, float hi) {
    unsigned r;
    asm("v_cvt_pk_bf16_f32 %0, %1, %2" : "=v"(r) : "v"(lo), "v"(hi));
    return r;
}

// Prep: [0,2048) NHWC repack ; [2048,2192) W->bf16 ; [2192,2201) w_off transpose.
__global__ __launch_bounds__(256) void k_prep(const float* __restrict__ x,
                                              const float* __restrict__ weight,
                                              const float* __restrict__ w_off) {
    int bid = blockIdx.x;
    if (bid < 2048) {
        int b  = bid >> 9;
        int y  = (bid >> 2) & 127;
        int jq = bid & 3;
        int oct = threadIdx.x & 7;
        int px  = threadIdx.x >> 3;        // 0..31
        int j   = jq*32 + px;
        const float* xp = x + ((size_t)(b*Cd + oct*8)*HWd + y*Wd + j);
        unsigned pk[4];
        #pragma unroll
        for (int e2 = 0; e2 < 4; ++e2) {
            float v0 = xp[(size_t)(2*e2    )*HWd];
            float v1 = xp[(size_t)(2*e2 + 1)*HWd];
            pk[e2] = (unsigned)f2bf(v0) | ((unsigned)f2bf(v1) << 16);
        }
        *(uint4*)(g_xt + ((size_t)(b*HWd) + y*Wd + j)*Cd + oct*8)
            = make_uint4(pk[0], pk[1], pk[2], pk[3]);
    } else if (bid < 2192) {
        int g = (bid - 2048)*256 + threadIdx.x;    // 64*576
        if (g < COd*576) {
            int co = g / 576, k = g % 576;
            int t = k >> 6, c = k & 63;            // k = t*64 + c
            g_wbf[g] = (short)f2bf(weight[(co*Cd + c)*9 + t]);
        }
    } else {
        int g = (bid - 2192)*256 + threadIdx.x;    // 9*64*4 = 2304
        if (g < 9*Cd*4) {
            int t = g >> 8, c = (g >> 2) & 63, o = g & 3;
            g_wtoff[g] = w_off[(o*Cd + c)*9 + t];
        }
    }
}

// Offsets conv: 2048 blocks, XCD-banded; lane=(px,oct); in-register butterfly reduce.
__global__ __launch_bounds__(256) void k_offsets(const float* __restrict__ b_off) {
    int orig = blockIdx.x;               // 2048
    int xcd = orig & 7, slot = orig >> 3;          // 0..255
    int g = xcd*2 + (slot >> 7);
    int s = slot & 127;
    int b = g >> 2;
    int i = (g & 3)*32 + (s >> 2);
    int jq = s & 3;

    int w = threadIdx.x >> 6, l = threadIdx.x & 63;
    int oct = l & 7, px8 = l >> 3;
    int px  = w*8 + px8;                 // 0..31
    int j   = jq*32 + px;

    const unsigned short* xb = g_xt + (size_t)b*HWd*Cd;
    f32x4 acc = {0.f, 0.f, 0.f, 0.f};
    #pragma unroll 3
    for (int t = 0; t < 9; ++t) {
        int yy = i + t/3 - 1, xx = j + t%3 - 1;
        if (yy < 0 || yy > 127 || xx < 0 || xx > 127) continue;
        uint4 u = *(const uint4*)(xb + (size_t)(yy*Wd + xx)*Cd + oct*8);
        unsigned aa[4] = {u.x, u.y, u.z, u.w};
        #pragma unroll
        for (int e = 0; e < 4; ++e) {
            int c = oct*8 + 2*e;
            f32x4 w0 = *(const f32x4*)(g_wtoff + (t*Cd + c    )*4);
            f32x4 w1 = *(const f32x4*)(g_wtoff + (t*Cd + c + 1)*4);
            acc += w0*bflo(aa[e]) + w1*bfhi(aa[e]);
        }
    }
    #pragma unroll
    for (int m = 1; m < 8; m <<= 1) {    // butterfly over oct lanes
        acc.x += __shfl_xor(acc.x, m, 64);
        acc.y += __shfl_xor(acc.y, m, 64);
        acc.z += __shfl_xor(acc.z, m, 64);
        acc.w += __shfl_xor(acc.w, m, 64);
    }
    if (oct == 0) {
        float off0 = acc.x + b_off[0];
        float off1 = acc.y + b_off[1];
        float s1   = fmaxf(acc.z + b_off[2], 0.f) + 1.f;
        float s2   = fmaxf(acc.w + b_off[3], 0.f) + 1.f;
        g_offs[(b*Hd + i)*Wd + j] = make_float4(off0, off1, s1, s2);
    }
}

// LDS-free deform: lane (pc,q) gathers its own B-fragment; wave = 16px x 64co.
__global__ __launch_bounds__(256, 4) void k_deform(const float* __restrict__ bias,
                                                   float* __restrict__ out) {
    int orig = blockIdx.x;               // 1024
    int xcd = orig & 7, slot = orig >> 3;          // 0..127
    int g = xcd*2 + (slot >> 6);
    int s = slot & 63;
    int b  = g >> 2;
    int i  = (g & 3)*32 + (s >> 1);
    int j0 = (s & 1) << 6;

    int w  = threadIdx.x >> 6;
    int l  = threadIdx.x & 63;
    int pc = l & 15, q = l >> 4;
    int j  = j0 + w*16 + pc;

    const unsigned short* xb = g_xt + (size_t)b*HWd*Cd;
    float4 o4 = g_offs[(b*Hd + i)*Wd + j];
    float off0 = o4.x, off1 = o4.y, s1 = o4.z, s2 = o4.w;

    f32x4 acc[4];
    #pragma unroll
    for (int cg = 0; cg < 4; ++cg) acc[cg] = (f32x4){0.f, 0.f, 0.f, 0.f};

    const short* wbase = g_wbf + pc*576 + q*8;   // + cg*16*576 + ks*32

    #pragma unroll 3
    for (int t = 0; t < 9; ++t) {
        float ys = (float)(i - 1) + (float)(t/3 - 1)*s1 + off0;
        float xs = (float)(j - 1) + (float)(t%3 - 1)*s2 + off1;
        float y0f = floorf(ys), x0f = floorf(xs);
        float wy = ys - y0f, wx = xs - x0f;
        float vy0 = (y0f >=  0.f && y0f <= 127.f) ? 1.f : 0.f;
        float vy1 = (y0f >= -1.f && y0f <= 126.f) ? 1.f : 0.f;
        float vx0 = (x0f >=  0.f && x0f <= 127.f) ? 1.f : 0.f;
        float vx1 = (x0f >= -1.f && x0f <= 126.f) ? 1.f : 0.f;
        float w00 = (1.f-wy)*(1.f-wx)*vy0*vx0, w01 = (1.f-wy)*wx*vy0*vx1;
        float w10 = wy*(1.f-wx)*vy1*vx0,       w11 = wy*wx*vy1*vx1;
        int iy0 = min(max((int)y0f,     0), 127), iy1 = min(max((int)y0f + 1, 0), 127);
        int ix0 = min(max((int)x0f,     0), 127), ix1 = min(max((int)x0f + 1, 0), 127);
        const unsigned short* p00 = xb + (size_t)(iy0*Wd + ix0)*Cd + q*8;
        const unsigned short* p01 = xb + (size_t)(iy0*Wd + ix1)*Cd + q*8;
        const unsigned short* p10 = xb + (size_t)(iy1*Wd + ix0)*Cd + q*8;
        const unsigned short* p11 = xb + (size_t)(iy1*Wd + ix1)*Cd + q*8;

        uint4 u00 = *(const uint4*)p00, u01 = *(const uint4*)p01;
        uint4 u10 = *(const uint4*)p10, u11 = *(const uint4*)p11;
        uint4 v00 = *(const uint4*)(p00 + 32), v01 = *(const uint4*)(p01 + 32);
        uint4 v10 = *(const uint4*)(p10 + 32), v11 = *(const uint4*)(p11 + 32);

        unsigned a00[4] = {u00.x,u00.y,u00.z,u00.w}, a01[4] = {u01.x,u01.y,u01.z,u01.w};
        unsigned a10[4] = {u10.x,u10.y,u10.z,u10.w}, a11[4] = {u11.x,u11.y,u11.z,u11.w};
        unsigned c00[4] = {v00.x,v00.y,v00.z,v00.w}, c01[4] = {v01.x,v01.y,v01.z,v01.w};
        unsigned c10[4] = {v10.x,v10.y,v10.z,v10.w}, c11[4] = {v11.x,v11.y,v11.z,v11.w};

        f32x2 w00v = {w00, w00}, w01v = {w01, w01};
        f32x2 w10v = {w10, w10}, w11v = {w11, w11};

        unsigned pe[4], po[4];
        #pragma unroll
        for (int e = 0; e < 4; ++e) {
            f32x2 r  = bf2(a00[e])*w00v + bf2(a01[e])*w01v
                     + bf2(a10[e])*w10v + bf2(a11[e])*w11v;
            pe[e] = cvtpk(r.x, r.y);
            f32x2 r2 = bf2(c00[e])*w00v + bf2(c01[e])*w01v
                     + bf2(c10[e])*w10v + bf2(c11[e])*w11v;
            po[e] = cvtpk(r2.x, r2.y);
        }
        uint4 beu = make_uint4(pe[0], pe[1], pe[2], pe[3]);
        uint4 bou = make_uint4(po[0], po[1], po[2], po[3]);
        short8 be = *(short8*)&beu;
        short8 bo = *(short8*)&bou;

        const int ks0 = 2*t;
        #pragma unroll
        for (int cg = 0; cg < 4; ++cg) {
            short8 av = *(const short8*)(wbase + (size_t)cg*16*576 + ks0*32);
            acc[cg] = __builtin_amdgcn_mfma_f32_16x16x32_bf16(av, be, acc[cg], 0, 0, 0);
        }
        #pragma unroll
        for (int cg = 0; cg < 4; ++cg) {
            short8 av = *(const short8*)(wbase + (size_t)cg*16*576 + ks0*32 + 32);
            acc[cg] = __builtin_amdgcn_mfma_f32_16x16x32_bf16(av, bo, acc[cg], 0, 0, 0);
        }
    }

    // D: col = pc (=px), row = q*4 + rr (+cg*16) -> co
    #pragma unroll
    for (int cg = 0; cg < 4; ++cg) {
        float4 bv = *(const float4*)(bias + cg*16 + q*4);
        float bb[4] = {bv.x, bv.y, bv.z, bv.w};
        #pragma unroll
        for (int rr = 0; rr < 4; ++rr) {
            int co = cg*16 + q*4 + rr;
            out[((size_t)(b*COd + co)*Hd + i)*Wd + j] = acc[cg][rr] + bb[rr];
        }
    }
}

extern "C" void kernel_launch(void* const* d_in, const int* in_sizes, int n_in,
                              void* d_out, int out_size, void* d_ws, size_t ws_size,
                              hipStream_t stream) {
    const float* x      = (const float*)d_in[0];
    const float* w_off  = (const float*)d_in[1];
    const float* b_off  = (const float*)d_in[2];
    const float* weight = (const float*)d_in[3];
    const float* bias   = (const float*)d_in[4];
    float* out = (float*)d_out;

    hipLaunchKernelGGL(k_prep,    dim3(2201), dim3(256), 0, stream, x, weight, w_off);
    hipLaunchKernelGGL(k_offsets, dim3(2048), dim3(256), 0, stream, b_off);
    hipLaunchKernelGGL(k_deform,  dim3(1024), dim3(256), 0, stream, bias, out);
}

// Round 8
// 108.218 us; speedup vs baseline: 1.3502x; 1.3502x over previous
//
#include <hip/hip_runtime.h>

#define Hd 128
#define Wd 128
#define Cd 64
#define COd 64
#define Bd 4
#define HWd (Hd*Wd)

typedef __attribute__((ext_vector_type(8))) short  short8;
typedef __attribute__((ext_vector_type(4))) float  f32x4;
typedef __attribute__((ext_vector_type(2))) float  f32x2;

// Static device scratch.
__device__ __align__(16) short g_wbf[COd*576];                   // bf16 W[co][k], k=t*64+c
__device__ __align__(16) float g_wtoff[9*Cd*4];                  // w_off^T [t][c][o]
__device__ float4 g_offs[Bd*HWd];                                // (off0, off1, s1, s2)
__device__ __align__(16) unsigned short g_xt[(size_t)Bd*HWd*Cd]; // bf16 NHWC x

static __device__ __forceinline__ unsigned short f2bf(float v) {
    unsigned u = __float_as_uint(v);
    u += 0x7FFFu + ((u >> 16) & 1u);   // RNE
    return (unsigned short)(u >> 16);
}
static __device__ __forceinline__ float bflo(unsigned u) { return __uint_as_float(u << 16); }
static __device__ __forceinline__ float bfhi(unsigned u) { return __uint_as_float(u & 0xFFFF0000u); }
static __device__ __forceinline__ f32x2 bf2(unsigned u) {
    return (f32x2){__uint_as_float(u << 16), __uint_as_float(u & 0xFFFF0000u)};
}
static __device__ __forceinline__ unsigned cvtpk(float lo, float hi) {
    unsigned r;
    asm("v_cvt_pk_bf16_f32 %0, %1, %2" : "=v"(r) : "v"(lo), "v"(hi));
    return r;
}

// Prep (r5 form, measured ~7us): [0,512) NHWC ; [512,656) W->bf16 ; [656,665) w_off^T.
__global__ __launch_bounds__(256) void k_prep(const float* __restrict__ x,
                                              const float* __restrict__ weight,
                                              const float* __restrict__ w_off) {
    int bid = blockIdx.x;
    if (bid < 512) {
        int b = bid >> 7, y = bid & 127;
        int px = threadIdx.x & 127;
        int h  = threadIdx.x >> 7;
        const float* xb = x + (size_t)b*Cd*HWd + y*Wd + px;
        unsigned short* ob = g_xt + ((size_t)(b*HWd) + y*Wd + px)*Cd + h*32;
        #pragma unroll
        for (int oct = 0; oct < 4; ++oct) {
            unsigned pk[4];
            #pragma unroll
            for (int e = 0; e < 4; ++e) {
                float v0 = xb[(size_t)(h*32 + oct*8 + 2*e    )*HWd];
                float v1 = xb[(size_t)(h*32 + oct*8 + 2*e + 1)*HWd];
                pk[e] = (unsigned)f2bf(v0) | ((unsigned)f2bf(v1) << 16);
            }
            *(uint4*)(ob + oct*8) = make_uint4(pk[0], pk[1], pk[2], pk[3]);
        }
    } else if (bid < 656) {
        int g = (bid - 512)*256 + threadIdx.x;     // 64*576
        if (g < COd*576) {
            int co = g / 576, k = g % 576;
            int t = k >> 6, c = k & 63;            // k = t*64 + c
            g_wbf[g] = (short)f2bf(weight[(co*Cd + c)*9 + t]);
        }
    } else {
        int g = (bid - 656)*256 + threadIdx.x;     // 9*64*4 = 2304
        if (g < 9*Cd*4) {
            int t = g >> 8, c = (g >> 2) & 63, o = g & 3;
            g_wtoff[g] = w_off[(o*Cd + c)*9 + t];
        }
    }
}

// Offsets conv (r7 form): 2048 blocks, XCD-banded, in-register butterfly reduce.
__global__ __launch_bounds__(256) void k_offsets(const float* __restrict__ b_off) {
    int orig = blockIdx.x;               // 2048
    int xcd = orig & 7, slot = orig >> 3;          // 0..255
    int g = xcd*2 + (slot >> 7);
    int s = slot & 127;
    int b = g >> 2;
    int i = (g & 3)*32 + (s >> 2);
    int jq = s & 3;

    int w = threadIdx.x >> 6, l = threadIdx.x & 63;
    int oct = l & 7, px8 = l >> 3;
    int px  = w*8 + px8;                 // 0..31
    int j   = jq*32 + px;

    const unsigned short* xb = g_xt + (size_t)b*HWd*Cd;
    f32x4 acc = {0.f, 0.f, 0.f, 0.f};
    #pragma unroll 3
    for (int t = 0; t < 9; ++t) {
        int yy = i + t/3 - 1, xx = j + t%3 - 1;
        if (yy < 0 || yy > 127 || xx < 0 || xx > 127) continue;
        uint4 u = *(const uint4*)(xb + (size_t)(yy*Wd + xx)*Cd + oct*8);
        unsigned aa[4] = {u.x, u.y, u.z, u.w};
        #pragma unroll
        for (int e = 0; e < 4; ++e) {
            int c = oct*8 + 2*e;
            f32x4 w0 = *(const f32x4*)(g_wtoff + (t*Cd + c    )*4);
            f32x4 w1 = *(const f32x4*)(g_wtoff + (t*Cd + c + 1)*4);
            acc += w0*bflo(aa[e]) + w1*bfhi(aa[e]);
        }
    }
    #pragma unroll
    for (int m = 1; m < 8; m <<= 1) {    // butterfly over oct lanes
        acc.x += __shfl_xor(acc.x, m, 64);
        acc.y += __shfl_xor(acc.y, m, 64);
        acc.z += __shfl_xor(acc.z, m, 64);
        acc.w += __shfl_xor(acc.w, m, 64);
    }
    if (oct == 0) {
        float off0 = acc.x + b_off[0];
        float off1 = acc.y + b_off[1];
        float s1   = fmaxf(acc.z + b_off[2], 0.f) + 1.f;
        float s2   = fmaxf(acc.w + b_off[3], 0.f) + 1.f;
        g_offs[(b*Hd + i)*Wd + j] = make_float4(off0, off1, s1, s2);
    }
}

#define GATHER(T, U00, U01, U10, U11, W00, W01, W10, W11)                         \
    {                                                                             \
        float ys = (float)(i - 1) + (float)((T)/3 - 1)*s1v + off0;                \
        float xs = (float)(jA - 1) + (float)((T)%3 - 1)*s2v + off1;               \
        float y0f = floorf(ys), x0f = floorf(xs);                                 \
        float wy = ys - y0f, wx = xs - x0f;                                       \
        float vy0 = (y0f >=  0.f && y0f <= 127.f) ? 1.f : 0.f;                    \
        float vy1 = (y0f >= -1.f && y0f <= 126.f) ? 1.f : 0.f;                    \
        float vx0 = (x0f >=  0.f && x0f <= 127.f) ? 1.f : 0.f;                    \
        float vx1 = (x0f >= -1.f && x0f <= 126.f) ? 1.f : 0.f;                    \
        W00 = (1.f-wy)*(1.f-wx)*vy0*vx0; W01 = (1.f-wy)*wx*vy0*vx1;               \
        W10 = wy*(1.f-wx)*vy1*vx0;       W11 = wy*wx*vy1*vx1;                     \
        int iy0 = min(max((int)y0f,     0), 127), iy1 = min(max((int)y0f+1,0),127);\
        int ix0 = min(max((int)x0f,     0), 127), ix1 = min(max((int)x0f+1,0),127);\
        U00 = *(const uint4*)(xb + (size_t)(iy0*Wd + ix0)*Cd + oct*8);            \
        U01 = *(const uint4*)(xb + (size_t)(iy0*Wd + ix1)*Cd + oct*8);            \
        U10 = *(const uint4*)(xb + (size_t)(iy1*Wd + ix0)*Cd + oct*8);            \
        U11 = *(const uint4*)(xb + (size_t)(iy1*Wd + ix1)*Cd + oct*8);            \
    }

#define PACK_STORE(BUF, U00, U01, U10, U11, W00, W01, W10, W11)                   \
    {                                                                             \
        unsigned a00[4] = {U00.x,U00.y,U00.z,U00.w};                              \
        unsigned a01[4] = {U01.x,U01.y,U01.z,U01.w};                              \
        unsigned a10[4] = {U10.x,U10.y,U10.z,U10.w};                              \
        unsigned a11[4] = {U11.x,U11.y,U11.z,U11.w};                              \
        f32x2 w00v = {W00, W00}, w01v = {W01, W01};                               \
        f32x2 w10v = {W10, W10}, w11v = {W11, W11};                               \
        unsigned pk[4];                                                           \
        _Pragma("unroll")                                                         \
        for (int e = 0; e < 4; ++e) {                                             \
            f32x2 r = bf2(a00[e])*w00v + bf2(a01[e])*w01v                         \
                    + bf2(a10[e])*w10v + bf2(a11[e])*w11v;                        \
            pk[e] = cvtpk(r.x, r.y);                                              \
        }                                                                         \
        lds_b[(((BUF)*2 + par)*2 + nt)*64 + slotA] = make_uint4(pk[0],pk[1],pk[2],pk[3]); \
    }

// Pipelined deform: 2048 blocks x 32 px; dbuf 8KB LDS; 1 barrier/tap.
__global__ __launch_bounds__(256) void k_deform(const float* __restrict__ bias,
                                                float* __restrict__ out) {
    __shared__ uint4 lds_b[2*2*2*64];    // [buf][parity][half][slot] = 8 KB
    int orig = blockIdx.x;               // 2048, same banding as k_offsets
    int xcd = orig & 7, slotB = orig >> 3;
    int g = xcd*2 + (slotB >> 7);
    int s = slotB & 127;
    int b = g >> 2;
    int i = (g & 3)*32 + (s >> 2);
    int j0 = (s & 3) << 5;

    int w = threadIdx.x >> 6, l = threadIdx.x & 63;
    // Phase-A identity (gather/pack)
    int oct = l & 7, px8 = l >> 3;
    int pxl = w*8 + px8;                 // 0..31
    int jA  = j0 + pxl;
    int nt = pxl >> 4, pcA = pxl & 15, qA = oct & 3, par = oct >> 2;
    int slotA = (pcA ^ (qA << 1)) + (qA << 4);
    // Phase-B identity (mfma/store)
    int pcB = l & 15, qB = l >> 4;
    int physl = (pcB ^ (qB << 1)) + (qB << 4);
    const short* wrow = g_wbf + (size_t)(w*16 + pcB)*576 + qB*8;

    const unsigned short* xb = g_xt + (size_t)b*HWd*Cd;
    float4 o4 = g_offs[(b*Hd + i)*Wd + jA];
    float off0 = o4.x, off1 = o4.y, s1v = o4.z, s2v = o4.w;

    f32x4 acc0 = {0.f,0.f,0.f,0.f};
    f32x4 acc1 = {0.f,0.f,0.f,0.f};

    uint4 gc00, gc01, gc10, gc11, gn00, gn01, gn10, gn11;
    float wc00, wc01, wc10, wc11, wn00, wn01, wn10, wn11;
    short8 ac0, ac1, an0, an1;

    GATHER(0, gc00, gc01, gc10, gc11, wc00, wc01, wc10, wc11);
    ac0 = *(const short8*)(wrow + 0*32);
    ac1 = *(const short8*)(wrow + 1*32);

    #pragma unroll
    for (int t = 0; t < 9; ++t) {
        if (t < 8) {
            GATHER(t+1, gn00, gn01, gn10, gn11, wn00, wn01, wn10, wn11);
            an0 = *(const short8*)(wrow + (2*t + 2)*32);
            an1 = *(const short8*)(wrow + (2*t + 3)*32);
        }
        PACK_STORE(t & 1, gc00, gc01, gc10, gc11, wc00, wc01, wc10, wc11);
        __syncthreads();
        {
            short8 b00 = *(const short8*)&lds_b[(((t&1)*2 + 0)*2 + 0)*64 + physl];
            short8 b01 = *(const short8*)&lds_b[(((t&1)*2 + 0)*2 + 1)*64 + physl];
            short8 b10 = *(const short8*)&lds_b[(((t&1)*2 + 1)*2 + 0)*64 + physl];
            short8 b11 = *(const short8*)&lds_b[(((t&1)*2 + 1)*2 + 1)*64 + physl];
            acc0 = __builtin_amdgcn_mfma_f32_16x16x32_bf16(ac0, b00, acc0, 0, 0, 0);
            acc1 = __builtin_amdgcn_mfma_f32_16x16x32_bf16(ac0, b01, acc1, 0, 0, 0);
            acc0 = __builtin_amdgcn_mfma_f32_16x16x32_bf16(ac1, b10, acc0, 0, 0, 0);
            acc1 = __builtin_amdgcn_mfma_f32_16x16x32_bf16(ac1, b11, acc1, 0, 0, 0);
        }
        if (t < 8) {
            gc00 = gn00; gc01 = gn01; gc10 = gn10; gc11 = gn11;
            wc00 = wn00; wc01 = wn01; wc10 = wn10; wc11 = wn11;
            ac0 = an0; ac1 = an1;
        }
    }

    // store: D col = pcB (=px), row = qB*4 + rr -> co = w*16 + qB*4 + rr
    #pragma unroll
    for (int rr = 0; rr < 4; ++rr) {
        int co = w*16 + qB*4 + rr;
        float bco = bias[co];
        size_t base = ((size_t)(b*COd + co)*Hd + i)*Wd + j0;
        out[base + pcB]      = acc0[rr] + bco;
        out[base + 16 + pcB] = acc1[rr] + bco;
    }
}

extern "C" void kernel_launch(void* const* d_in, const int* in_sizes, int n_in,
                              void* d_out, int out_size, void* d_ws, size_t ws_size,
                              hipStream_t stream) {
    const float* x      = (const float*)d_in[0];
    const float* w_off  = (const float*)d_in[1];
    const float* b_off  = (const float*)d_in[2];
    const float* weight = (const float*)d_in[3];
    const float* bias   = (const float*)d_in[4];
    float* out = (float*)d_out;

    hipLaunchKernelGGL(k_prep,    dim3(665),  dim3(256), 0, stream, x, weight, w_off);
    hipLaunchKernelGGL(k_offsets, dim3(2048), dim3(256), 0, stream, b_off);
    hipLaunchKernelGGL(k_deform,  dim3(2048), dim3(256), 0, stream, bias, out);
}

// Round 9
// 59.740 us; speedup vs baseline: 2.4459x; 1.8115x over previous
//
#include <hip/hip_runtime.h>

#define Hd 128
#define Wd 128
#define Cd 64
#define COd 64
#define Bd 4
#define HWd (Hd*Wd)

typedef __attribute__((ext_vector_type(8))) short  short8;
typedef __attribute__((ext_vector_type(4))) float  f32x4;
typedef __attribute__((ext_vector_type(2))) float  f32x2;

// Static device scratch.
__device__ __align__(16) short g_wbf[COd*576];                   // bf16 W[co][k], k=t*64+c
__device__ __align__(16) short g_woffbf[16*576];                 // bf16 w_off padded to 16 rows
__device__ float4 g_offs[Bd*HWd];                                // (off0, off1, s1, s2)
__device__ __align__(16) unsigned short g_xt[(size_t)Bd*HWd*Cd]; // bf16 NHWC x

static __device__ __forceinline__ unsigned short f2bf(float v) {
    unsigned u = __float_as_uint(v);
    u += 0x7FFFu + ((u >> 16) & 1u);   // RNE
    return (unsigned short)(u >> 16);
}
static __device__ __forceinline__ f32x2 bf2(unsigned u) {
    return (f32x2){__uint_as_float(u << 16), __uint_as_float(u & 0xFFFF0000u)};
}
static __device__ __forceinline__ unsigned cvtpk(float lo, float hi) {
    unsigned r;
    asm("v_cvt_pk_bf16_f32 %0, %1, %2" : "=v"(r) : "v"(lo), "v"(hi));
    return r;
}

// Prep: [0,512) NHWC ; [512,656) W->bf16 ; [656,692) w_off padded bf16.
__global__ __launch_bounds__(256) void k_prep(const float* __restrict__ x,
                                              const float* __restrict__ weight,
                                              const float* __restrict__ w_off) {
    int bid = blockIdx.x;
    if (bid < 512) {
        int b = bid >> 7, y = bid & 127;
        int px = threadIdx.x & 127;
        int h  = threadIdx.x >> 7;
        const float* xb = x + (size_t)b*Cd*HWd + y*Wd + px;
        unsigned short* ob = g_xt + ((size_t)(b*HWd) + y*Wd + px)*Cd + h*32;
        #pragma unroll
        for (int oct = 0; oct < 4; ++oct) {
            unsigned pk[4];
            #pragma unroll
            for (int e = 0; e < 4; ++e) {
                float v0 = xb[(size_t)(h*32 + oct*8 + 2*e    )*HWd];
                float v1 = xb[(size_t)(h*32 + oct*8 + 2*e + 1)*HWd];
                pk[e] = (unsigned)f2bf(v0) | ((unsigned)f2bf(v1) << 16);
            }
            *(uint4*)(ob + oct*8) = make_uint4(pk[0], pk[1], pk[2], pk[3]);
        }
    } else if (bid < 656) {
        int g = (bid - 512)*256 + threadIdx.x;     // 64*576
        if (g < COd*576) {
            int co = g / 576, k = g % 576;
            int t = k >> 6, c = k & 63;            // k = t*64 + c
            g_wbf[g] = (short)f2bf(weight[(co*Cd + c)*9 + t]);
        }
    } else {
        int g = (bid - 656)*256 + threadIdx.x;     // 16*576 = 9216
        if (g < 16*576) {
            int row = g / 576, k = g % 576;
            int t = k >> 6, c = k & 63;
            g_woffbf[g] = (row < 4) ? (short)f2bf(w_off[(row*Cd + c)*9 + t]) : (short)0;
        }
    }
}

// Offsets conv as MFMA mini-GEMM: 1024 blocks x 64 px; canonical taps = direct loads.
__global__ __launch_bounds__(256) void k_offs(const float* __restrict__ b_off) {
    int orig = blockIdx.x;               // 1024, XCD-banded
    int xcd = orig & 7, slot = orig >> 3;          // 0..127
    int g = xcd*2 + (slot >> 6);
    int s = slot & 63;
    int b  = g >> 2;
    int i  = (g & 3)*32 + (s >> 1);
    int j0 = (s & 1) << 6;

    int w  = threadIdx.x >> 6;
    int l  = threadIdx.x & 63;
    int pc = l & 15, q = l >> 4;
    int j  = j0 + w*16 + pc;

    const unsigned short* xb = g_xt + (size_t)b*HWd*Cd;
    const short* arow = g_woffbf + pc*576 + q*8;

    f32x4 acc = {0.f, 0.f, 0.f, 0.f};
    #pragma unroll
    for (int t = 0; t < 9; ++t) {
        int yy = i + t/3 - 1, xx = j + t%3 - 1;
        bool ok = (yy >= 0) & (yy <= 127) & (xx >= 0) & (xx <= 127);
        const unsigned short* p = xb + (size_t)(yy*Wd + xx)*Cd + q*8;
        uint4 u0 = ok ? *(const uint4*)p        : make_uint4(0,0,0,0);
        uint4 u1 = ok ? *(const uint4*)(p + 32) : make_uint4(0,0,0,0);
        short8 b0 = *(short8*)&u0;
        short8 b1 = *(short8*)&u1;
        short8 a0 = *(const short8*)(arow + (2*t    )*32);
        short8 a1 = *(const short8*)(arow + (2*t + 1)*32);
        acc = __builtin_amdgcn_mfma_f32_16x16x32_bf16(a0, b0, acc, 0, 0, 0);
        acc = __builtin_amdgcn_mfma_f32_16x16x32_bf16(a1, b1, acc, 0, 0, 0);
    }
    if (q == 0) {   // lanes 0..15: D rows 0..3 for pixel pc
        float o0 = acc[0] + b_off[0];
        float o1 = acc[1] + b_off[1];
        float o2 = fmaxf(acc[2] + b_off[2], 0.f) + 1.f;
        float o3 = fmaxf(acc[3] + b_off[3], 0.f) + 1.f;
        g_offs[(b*Hd + i)*Wd + j] = make_float4(o0, o1, o2, o3);
    }
}

#define GATHER(T, U00, U01, U10, U11, W00, W01, W10, W11)                         \
    {                                                                             \
        float ys = (float)(i - 1) + (float)((T)/3 - 1)*s1v + off0;                \
        float xs = (float)(jA - 1) + (float)((T)%3 - 1)*s2v + off1;               \
        float y0f = floorf(ys), x0f = floorf(xs);                                 \
        float wy = ys - y0f, wx = xs - x0f;                                       \
        float vy0 = (y0f >=  0.f && y0f <= 127.f) ? 1.f : 0.f;                    \
        float vy1 = (y0f >= -1.f && y0f <= 126.f) ? 1.f : 0.f;                    \
        float vx0 = (x0f >=  0.f && x0f <= 127.f) ? 1.f : 0.f;                    \
        float vx1 = (x0f >= -1.f && x0f <= 126.f) ? 1.f : 0.f;                    \
        W00 = (1.f-wy)*(1.f-wx)*vy0*vx0; W01 = (1.f-wy)*wx*vy0*vx1;               \
        W10 = wy*(1.f-wx)*vy1*vx0;       W11 = wy*wx*vy1*vx1;                     \
        int iy0 = min(max((int)y0f,     0), 127), iy1 = min(max((int)y0f+1,0),127);\
        int ix0 = min(max((int)x0f,     0), 127), ix1 = min(max((int)x0f+1,0),127);\
        U00 = *(const uint4*)(xb + (size_t)(iy0*Wd + ix0)*Cd + oct*8);            \
        U01 = *(const uint4*)(xb + (size_t)(iy0*Wd + ix1)*Cd + oct*8);            \
        U10 = *(const uint4*)(xb + (size_t)(iy1*Wd + ix0)*Cd + oct*8);            \
        U11 = *(const uint4*)(xb + (size_t)(iy1*Wd + ix1)*Cd + oct*8);            \
    }

#define PACK_STORE(BUF, U00, U01, U10, U11, W00, W01, W10, W11)                   \
    {                                                                             \
        unsigned a00[4] = {U00.x,U00.y,U00.z,U00.w};                              \
        unsigned a01[4] = {U01.x,U01.y,U01.z,U01.w};                              \
        unsigned a10[4] = {U10.x,U10.y,U10.z,U10.w};                              \
        unsigned a11[4] = {U11.x,U11.y,U11.z,U11.w};                              \
        f32x2 w00v = {W00, W00}, w01v = {W01, W01};                               \
        f32x2 w10v = {W10, W10}, w11v = {W11, W11};                               \
        unsigned pk[4];                                                           \
        _Pragma("unroll")                                                         \
        for (int e = 0; e < 4; ++e) {                                             \
            f32x2 r = bf2(a00[e])*w00v + bf2(a01[e])*w01v                         \
                    + bf2(a10[e])*w10v + bf2(a11[e])*w11v;                        \
            pk[e] = cvtpk(r.x, r.y);                                              \
        }                                                                         \
        lds_b[(((BUF)*2 + par)*2 + nt)*64 + slotA] = make_uint4(pk[0],pk[1],pk[2],pk[3]); \
    }

// Pipelined deform (r8 form): 2048 blocks x 32 px; dbuf 8KB LDS; 1 barrier/tap.
__global__ __launch_bounds__(256) void k_deform(const float* __restrict__ bias,
                                                float* __restrict__ out) {
    __shared__ uint4 lds_b[2*2*2*64];    // [buf][parity][half][slot] = 8 KB
    int orig = blockIdx.x;               // 2048, same banding as k_offs
    int xcd = orig & 7, slotB = orig >> 3;
    int g = xcd*2 + (slotB >> 7);
    int s = slotB & 127;
    int b = g >> 2;
    int i = (g & 3)*32 + (s >> 2);
    int j0 = (s & 3) << 5;

    int w = threadIdx.x >> 6, l = threadIdx.x & 63;
    // Phase-A identity (gather/pack)
    int oct = l & 7, px8 = l >> 3;
    int pxl = w*8 + px8;                 // 0..31
    int jA  = j0 + pxl;
    int nt = pxl >> 4, pcA = pxl & 15, qA = oct & 3, par = oct >> 2;
    int slotA = (pcA ^ (qA << 1)) + (qA << 4);
    // Phase-B identity (mfma/store)
    int pcB = l & 15, qB = l >> 4;
    int physl = (pcB ^ (qB << 1)) + (qB << 4);
    const short* wrow = g_wbf + (size_t)(w*16 + pcB)*576 + qB*8;

    const unsigned short* xb = g_xt + (size_t)b*HWd*Cd;
    float4 o4 = g_offs[(b*Hd + i)*Wd + jA];
    float off0 = o4.x, off1 = o4.y, s1v = o4.z, s2v = o4.w;

    f32x4 acc0 = {0.f,0.f,0.f,0.f};
    f32x4 acc1 = {0.f,0.f,0.f,0.f};

    uint4 gc00, gc01, gc10, gc11, gn00, gn01, gn10, gn11;
    float wc00, wc01, wc10, wc11, wn00, wn01, wn10, wn11;
    short8 ac0, ac1, an0, an1;

    GATHER(0, gc00, gc01, gc10, gc11, wc00, wc01, wc10, wc11);
    ac0 = *(const short8*)(wrow + 0*32);
    ac1 = *(const short8*)(wrow + 1*32);

    #pragma unroll
    for (int t = 0; t < 9; ++t) {
        if (t < 8) {
            GATHER(t+1, gn00, gn01, gn10, gn11, wn00, wn01, wn10, wn11);
            an0 = *(const short8*)(wrow + (2*t + 2)*32);
            an1 = *(const short8*)(wrow + (2*t + 3)*32);
        }
        PACK_STORE(t & 1, gc00, gc01, gc10, gc11, wc00, wc01, wc10, wc11);
        __syncthreads();
        {
            short8 b00 = *(const short8*)&lds_b[(((t&1)*2 + 0)*2 + 0)*64 + physl];
            short8 b01 = *(const short8*)&lds_b[(((t&1)*2 + 0)*2 + 1)*64 + physl];
            short8 b10 = *(const short8*)&lds_b[(((t&1)*2 + 1)*2 + 0)*64 + physl];
            short8 b11 = *(const short8*)&lds_b[(((t&1)*2 + 1)*2 + 1)*64 + physl];
            acc0 = __builtin_amdgcn_mfma_f32_16x16x32_bf16(ac0, b00, acc0, 0, 0, 0);
            acc1 = __builtin_amdgcn_mfma_f32_16x16x32_bf16(ac0, b01, acc1, 0, 0, 0);
            acc0 = __builtin_amdgcn_mfma_f32_16x16x32_bf16(ac1, b10, acc0, 0, 0, 0);
            acc1 = __builtin_amdgcn_mfma_f32_16x16x32_bf16(ac1, b11, acc1, 0, 0, 0);
        }
        if (t < 8) {
            gc00 = gn00; gc01 = gn01; gc10 = gn10; gc11 = gn11;
            wc00 = wn00; wc01 = wn01; wc10 = wn10; wc11 = wn11;
            ac0 = an0; ac1 = an1;
        }
    }

    // store: D col = pcB (=px), row = qB*4 + rr -> co = w*16 + qB*4 + rr
    #pragma unroll
    for (int rr = 0; rr < 4; ++rr) {
        int co = w*16 + qB*4 + rr;
        float bco = bias[co];
        size_t base = ((size_t)(b*COd + co)*Hd + i)*Wd + j0;
        out[base + pcB]      = acc0[rr] + bco;
        out[base + 16 + pcB] = acc1[rr] + bco;
    }
}

extern "C" void kernel_launch(void* const* d_in, const int* in_sizes, int n_in,
                              void* d_out, int out_size, void* d_ws, size_t ws_size,
                              hipStream_t stream) {
    const float* x      = (const float*)d_in[0];
    const float* w_off  = (const float*)d_in[1];
    const float* b_off  = (const float*)d_in[2];
    const float* weight = (const float*)d_in[3];
    const float* bias   = (const float*)d_in[4];
    float* out = (float*)d_out;

    hipLaunchKernelGGL(k_prep,   dim3(692),  dim3(256), 0, stream, x, weight, w_off);
    hipLaunchKernelGGL(k_offs,   dim3(1024), dim3(256), 0, stream, b_off);
    hipLaunchKernelGGL(k_deform, dim3(2048), dim3(256), 0, stream, bias, out);
}